// Round 4
// baseline (349.309 us; speedup 1.0000x reference)
//
#include <hip/hip_runtime.h>
#include <hip/hip_bf16.h>

#define BM 128
// BK = 64, staged as two bank-safe BK=32 half-tiles. BN is a template param (64 or 128).

typedef __bf16 bf16x8 __attribute__((ext_vector_type(8)));
typedef float f32x4 __attribute__((ext_vector_type(4)));
typedef unsigned short u16;

__device__ __forceinline__ u16 f2bf(float f) {
    __bf16 b = (__bf16)f;
    return __builtin_bit_cast(u16, b);
}
__device__ __forceinline__ float bf2f(u16 u) {
    __bf16 b = __builtin_bit_cast(__bf16, u);
    return (float)b;
}

__device__ __forceinline__ void gload_lds16(const void* g, void* l) {
    __builtin_amdgcn_global_load_lds(
        (const __attribute__((address_space(1))) void*)g,
        (__attribute__((address_space(3))) void*)l,
        16, 0, 0);
}

// Generic C = A @ B^T GEMM, A [M,K] bf16 row-major (lda), Bt [N,K] bf16 row-major (ldb).
// MODE 2: bf16 out = exp(acc*scale), causal-masked (raw attention numerator P)
// MODE 3: bf16 out = bf16_resid + acc * linv[row]  (PV * 1/l + residual -> h; linv via `bias`)
// MODE 4: bf16 out = relu(acc + bias)              (FFN1)
// MODE 5: fp32 out = acc + bias + bf16(resid)      (FFN2 + residual)
// MODE 6: merged QKV: n0<512 -> bf16 row-major QK + bias; else Vt transposed + bias
// causal: 0 none, 2 clip K-loop at diagonal + complementary by-pairing (PV),
//         3 triangular blockIdx.x decode (scores; bz = blockIdx.y)
template <int MODE, int BN_>
__global__ __launch_bounds__(256)
void gemm_bt(const u16* __restrict__ A, int lda, long long a_bs,
             const u16* __restrict__ Bt, int ldb, long long b_bs,
             int Kdim, int ldc, long long c_bs,
             const float* __restrict__ bias, float scale,
             const void* __restrict__ resid, long long r_bs,
             void* __restrict__ out, int causal)
{
    constexpr int NJ = BN_ / 32;   // B fragments per wave (4 or 2)
    constexpr int JW = BN_ / 2;    // wave column span (64 or 32)

    int bx = blockIdx.x, by = blockIdx.y, bz = blockIdx.z;
    if (causal == 3) {
        // triangular decode: blockIdx.x = by*(by+1)/2 + bx, bz = blockIdx.y
        const int t = blockIdx.x;
        int byy = (int)((sqrtf(8.f * (float)t + 1.f) - 1.f) * 0.5f);
        while ((byy + 1) * (byy + 2) / 2 <= t) byy++;
        while (byy * (byy + 1) / 2 > t) byy--;
        by = byy; bx = t - byy * (byy + 1) / 2; bz = blockIdx.y;
    }
    if (causal == 2 && bz >= 2) by = (int)gridDim.y - 1 - by;  // pair long/short K rows per CU
    const int kend = (causal == 2) ? min(Kdim, (by + 1) * BM) : Kdim;

    A  += (long long)bz * a_bs;
    Bt += (long long)bz * b_bs;

    const int m0 = by * BM, n0 = bx * BN_;
    const int tid = threadIdx.x;
    const int wave = tid >> 6, lane = tid & 63;
    const int wy = wave >> 1, wx = wave & 1;
    const int lr = lane >> 2, lc8 = (lane & 3) * 8;
    const int lane15 = lane & 15, kq = lane >> 4;

    __shared__ __align__(16) u16 As[2][BM * 32];
    __shared__ __align__(16) u16 Bs[2][BN_ * 32];

    f32x4 acc[4][NJ] = {};

    for (int k0 = 0; k0 < kend; k0 += 64) {
        __syncthreads();
        #pragma unroll
        for (int h = 0; h < 2; h++) {
            const int kh = k0 + h * 32 + lc8;
            #pragma unroll
            for (int it = 0; it < 2; it++) {
                const int row = wave * 16 + it * 64 + lr;
                gload_lds16(A + (size_t)(m0 + row) * lda + kh,
                            &As[h][(wave * 16 + it * 64) * 32]);
            }
            if (BN_ == 128) {
                #pragma unroll
                for (int it = 0; it < 2; it++) {
                    const int row = wave * 16 + it * 64 + lr;
                    gload_lds16(Bt + (size_t)(n0 + row) * ldb + kh,
                                &Bs[h][(wave * 16 + it * 64) * 32]);
                }
            } else {
                const int row = wave * 16 + lr;
                gload_lds16(Bt + (size_t)(n0 + row) * ldb + kh,
                            &Bs[h][(wave * 16) * 32]);
            }
        }
        __syncthreads();

        #pragma unroll
        for (int h = 0; h < 2; h++) {
            bf16x8 av[4], bv[NJ];
            #pragma unroll
            for (int i = 0; i < 4; i++)
                av[i] = *(const bf16x8*)&As[h][(wy * 64 + i * 16 + lane15) * 32 + kq * 8];
            #pragma unroll
            for (int j = 0; j < NJ; j++)
                bv[j] = *(const bf16x8*)&Bs[h][(wx * JW + j * 16 + lane15) * 32 + kq * 8];
            #pragma unroll
            for (int i = 0; i < 4; i++)
                #pragma unroll
                for (int j = 0; j < NJ; j++)
                    acc[i][j] = __builtin_amdgcn_mfma_f32_16x16x32_bf16(av[i], bv[j], acc[i][j], 0, 0, 0);
        }
    }

    // Epilogue. C/D layout (m89-verified): col = lane&15, row = (lane>>4)*4 + reg.
    if (MODE == 6 && n0 >= 512) {
        // Vt[b][c-512][s] transposed write, ldc_vt = 1024 cols, S=2048
        u16* o = (u16*)resid;  // second output pointer
        #pragma unroll
        for (int i = 0; i < 4; i++) {
            const int r = m0 + wy * 64 + i * 16 + kq * 4;
            const size_t base = (size_t)(r >> 11) * 1024 * 2048 + (r & 2047);
            #pragma unroll
            for (int j = 0; j < NJ; j++) {
                const int c = n0 + wx * JW + j * 16 + lane15;
                const float bj = bias[c];
                ushort4 pk;
                pk.x = f2bf(acc[i][j][0] + bj);
                pk.y = f2bf(acc[i][j][1] + bj);
                pk.z = f2bf(acc[i][j][2] + bj);
                pk.w = f2bf(acc[i][j][3] + bj);
                *(ushort4*)&o[base + (size_t)(c - 512) * 2048] = pk;
            }
        }
    } else {
        #pragma unroll
        for (int i = 0; i < 4; i++) {
            const int rl = m0 + wy * 64 + i * 16 + kq * 4;
            #pragma unroll
            for (int j = 0; j < NJ; j++) {
                const int c = n0 + wx * JW + j * 16 + lane15;
                float bj = 0.f;
                if (MODE == 4 || MODE == 5 || MODE == 6) bj = bias[c];
                #pragma unroll
                for (int rg = 0; rg < 4; rg++) {
                    const int r = rl + rg;
                    const size_t idx = (size_t)bz * c_bs + (size_t)r * ldc + c;
                    const float v = acc[i][j][rg];
                    if (MODE == 2) {
                        float p = __expf(v * scale);
                        if (c > r) p = 0.f;          // causal mask inside diagonal tile
                        ((u16*)out)[idx] = f2bf(p);
                    } else if (MODE == 3) {
                        const u16* xr = (const u16*)resid;
                        const float linv = bias[(size_t)bz * 2048 + r];
                        const float h = bf2f(xr[(size_t)bz * r_bs + (size_t)r * ldc + c]) + v * linv;
                        ((u16*)out)[idx] = f2bf(h);
                    } else if (MODE == 4) {
                        ((u16*)out)[idx] = f2bf(fmaxf(v + bj, 0.f));
                    } else if (MODE == 5) {
                        const u16* hb = (const u16*)resid;
                        ((float*)out)[idx] = v + bj + bf2f(hb[(size_t)r * ldc + c]);
                    } else if (MODE == 6) {
                        ((u16*)out)[idx] = f2bf(v + bj);
                    }
                }
            }
        }
    }
}

// Convert x to bf16; build transposed bf16 weights; concat fp32 biases.
__global__ __launch_bounds__(256)
void prep_kernel(const float* __restrict__ x,
                 const float* __restrict__ Wq, const float* __restrict__ bq,
                 const float* __restrict__ Wk, const float* __restrict__ bk,
                 const float* __restrict__ Wv, const float* __restrict__ bv,
                 const float* __restrict__ W1, const float* __restrict__ b1,
                 const float* __restrict__ W2, const float* __restrict__ b2,
                 u16* __restrict__ xb, u16* __restrict__ WqkT, u16* __restrict__ WvT,
                 u16* __restrict__ W1T, u16* __restrict__ W2T, float* __restrict__ biasv)
{
    const int NX = 8388608, NQK = 524288, NW = 1048576;
    const int total = NX + NQK + 3 * NW + 3584;
    for (int i = blockIdx.x * blockDim.x + threadIdx.x; i < total; i += gridDim.x * blockDim.x) {
        int t = i;
        if (t < NX) { xb[t] = f2bf(x[t]); continue; }
        t -= NX;
        if (t < NQK) {
            const int n = t >> 10, k = t & 1023;
            const float v = (n < 256) ? Wq[k * 256 + n] : Wk[k * 256 + (n - 256)];
            WqkT[t] = f2bf(v); continue;
        }
        t -= NQK;
        if (t < NW) { const int n = t >> 10, k = t & 1023; WvT[t] = f2bf(Wv[(size_t)k * 1024 + n]); continue; }
        t -= NW;
        if (t < NW) { const int n = t >> 10, k = t & 1023; W1T[t] = f2bf(W1[(size_t)k * 1024 + n]); continue; }
        t -= NW;
        if (t < NW) { const int n = t >> 10, k = t & 1023; W2T[t] = f2bf(W2[(size_t)k * 1024 + n]); continue; }
        t -= NW;
        if (t < 512)       biasv[t] = (t < 256) ? bq[t] : bk[t - 256];
        else if (t < 1536) biasv[t] = bv[t - 512];
        else if (t < 2560) biasv[t] = b1[t - 1536];
        else               biasv[t] = b2[t - 2560];
    }
}

__device__ __forceinline__ float wave_sum(float v) {
    #pragma unroll
    for (int off = 32; off > 0; off >>= 1) v += __shfl_xor(v, off, 64);
    return v;
}

// One block per (b,q) row. Reads raw bf16 exp-scores (P), computes l = sum(P),
// writes normalized fp32 attn (zeros above diagonal, over the 0xAA poison) and 1/l.
__global__ __launch_bounds__(256)
void norm_kernel(const u16* __restrict__ attnb, float* __restrict__ attn,
                 float* __restrict__ linv)
{
    const int S = 2048;
    const int row = blockIdx.x;
    const int q = row & (S - 1);
    const int valid = q + 1;
    const int kpad = (valid + 127) & ~127;
    const u16* brow = attnb + (size_t)row * S;
    float* srow = attn + (size_t)row * S;
    __shared__ float red[4];
    const int tid = threadIdx.x, wv = tid >> 6, ln = tid & 63;

    float vals[8];
    float lsum = 0.f;
    int cnt = 0;
    for (int k = tid; k < kpad; k += 256) { const float v = bf2f(brow[k]); vals[cnt++] = v; lsum += v; }
    lsum = wave_sum(lsum);
    if (ln == 0) red[wv] = lsum;
    __syncthreads();
    const float rinv = 1.f / (red[0] + red[1] + red[2] + red[3]);

    cnt = 0;
    for (int k = tid; k < kpad; k += 256) { srow[k] = (k < valid) ? vals[cnt] * rinv : 0.f; cnt++; }
    for (int k = kpad + tid; k < S; k += 256) srow[k] = 0.f;
    if (tid == 0) linv[row] = rinv;
}

extern "C" void kernel_launch(void* const* d_in, const int* in_sizes, int n_in,
                              void* d_out, int out_size, void* d_ws, size_t ws_size,
                              hipStream_t stream)
{
    const float* x  = (const float*)d_in[0];
    const float* Wq = (const float*)d_in[1];
    const float* bq = (const float*)d_in[2];
    const float* Wk = (const float*)d_in[3];
    const float* bk = (const float*)d_in[4];
    const float* Wv = (const float*)d_in[5];
    const float* bv = (const float*)d_in[6];
    const float* W1 = (const float*)d_in[7];
    const float* b1 = (const float*)d_in[8];
    const float* W2 = (const float*)d_in[9];
    const float* b2 = (const float*)d_in[10];

    const int B = 4, S = 2048, D = 1024, BS = B * S;

    char* ws = (char*)d_ws;
    u16*   xb    = (u16*)(ws + 0);            // 16 MB, aliased by h_b after G4
    u16*   WqkT  = (u16*)(ws + 16777216);     // 1 MB  (contiguous with WvT -> merged B of N=1536)
    u16*   WvT   = (u16*)(ws + 17825792);     // 2 MB
    u16*   W1T   = (u16*)(ws + 19922944);     // 2 MB
    u16*   W2T   = (u16*)(ws + 22020096);     // 2 MB
    float* biasv = (float*)(ws + 24117248);   // 16 KB: [bq|bk][bv][b1][b2]
    u16*   QK    = (u16*)(ws + 24133632);     // 8 MB: [8192][512] = [Q|K]
    u16*   Vt    = (u16*)(ws + 32522240);     // 16 MB: [4][1024][2048]
    u16*   attnb = (u16*)(ws + 49299456);     // 32 MB raw exp-P, aliased by ff1 after G4
    float* linv  = (float*)(ws + 83886080);   // 32 KB (ws is ~400 MB per harness fill)
    u16*   hb    = xb;
    u16*   ff1   = attnb;

    float* out0 = (float*)d_out;
    float* attn = out0 + (size_t)BS * D;

    const dim3 blk(256);

    prep_kernel<<<dim3(2048), blk, 0, stream>>>(x, Wq, bq, Wk, bk, Wv, bv, W1, b1, W2, b2,
                                                xb, WqkT, WvT, W1T, W2T, biasv);

    // G12 merged: [Q|K|V] = x @ [Wq|Wk|Wv] + bias   (M=8192, N=1536, K=1024, BN=64 -> 6 blk/CU)
    gemm_bt<6, 64><<<dim3(24, 64, 1), blk, 0, stream>>>(
        xb, 1024, 0, WqkT, 1024, 0, 1024, 512, 0,
        biasv, 1.f, Vt, 0, QK, 0);

    // G3: P = exp(Q @ K^T / 16), causal-masked, bf16, triangular grid (544 blocks)
    gemm_bt<2, 128><<<dim3(136, 4, 1), blk, 0, stream>>>(
        QK, 512, (long long)S * 512, QK + 256, 512, (long long)S * 512,
        256, S, (long long)S * S, nullptr, 0.0625f, nullptr, 0, attnb, 3);

    // normalize: attn_fp32 = P / l (d_out), linv = 1/l
    norm_kernel<<<dim3(BS), blk, 0, stream>>>(attnb, attn, linv);

    // G4: h = bf16(x) + (P @ V) * linv  (BN=64 -> 1024 blocks, K clipped at diagonal,
    //     complementary by-pairing for CU load balance; linv passed via `bias`)
    gemm_bt<3, 64><<<dim3(16, 16, 4), blk, 0, stream>>>(
        attnb, S, (long long)S * S, Vt, S, (long long)D * S,
        S, D, (long long)S * D, linv, 1.f, xb, (long long)S * D, hb, 2);

    // G5: ff1 = relu(h @ W1 + b1)  (M=8192, N=1024, K=1024, BN=64 -> 4 blk/CU)
    gemm_bt<4, 64><<<dim3(16, 64, 1), blk, 0, stream>>>(
        hb, 1024, 0, W1T, 1024, 0, 1024, 1024, 0,
        biasv + 1536, 1.f, nullptr, 0, ff1, 0);

    // G6: out0 = h + ff1 @ W2 + b2  (M=8192, N=1024, K=1024, BN=64)
    gemm_bt<5, 64><<<dim3(16, 64, 1), blk, 0, stream>>>(
        ff1, 1024, 0, W2T, 1024, 0, 1024, 1024, 0,
        biasv + 2560, 1.f, hb, 0, out0, 0);
}

// Round 5
// 330.346 us; speedup vs baseline: 1.0574x; 1.0574x over previous
//
#include <hip/hip_runtime.h>
#include <hip/hip_bf16.h>

#define BM 128
#define BN 128
// BK = 64, staged as two bank-safe BK=32 half-tiles (m97 layout per half)

typedef __bf16 bf16x8 __attribute__((ext_vector_type(8)));
typedef float f32x4 __attribute__((ext_vector_type(4)));
typedef unsigned short u16;

__device__ __forceinline__ u16 f2bf(float f) {
    __bf16 b = (__bf16)f;
    return __builtin_bit_cast(u16, b);
}
__device__ __forceinline__ float bf2f(u16 u) {
    __bf16 b = __builtin_bit_cast(__bf16, u);
    return (float)b;
}

__device__ __forceinline__ void gload_lds16(const void* g, void* l) {
    __builtin_amdgcn_global_load_lds(
        (const __attribute__((address_space(1))) void*)g,
        (__attribute__((address_space(3))) void*)l,
        16, 0, 0);
}

// Generic C = A @ B^T GEMM, A [M,K] bf16 row-major (lda), Bt [N,K] bf16 row-major (ldb).
// MODE 2: bf16 out = exp(acc*scale), causal-masked (raw attention numerator P)
// MODE 3: bf16 out = bf16_resid + acc * linv[row]  (PV * 1/l + residual -> h; linv via `bias`)
// MODE 4: bf16 out = relu(acc + bias)              (FFN1)
// MODE 5: fp32 out = acc + bias + bf16(resid)      (FFN2 + residual)
// MODE 6: merged QKV: n0<512 -> bf16 row-major QK + bias; else Vt transposed + bias
// causal: 0 none, 2 clip K-loop at diagonal + complementary by-pairing (PV),
//         3 triangular blockIdx.x decode (scores; bz = blockIdx.y)
template <int MODE>
__global__ __launch_bounds__(256)
void gemm_bt(const u16* __restrict__ A, int lda, long long a_bs,
             const u16* __restrict__ Bt, int ldb, long long b_bs,
             int Kdim, int ldc, long long c_bs,
             const float* __restrict__ bias, float scale,
             const void* __restrict__ resid, long long r_bs,
             void* __restrict__ out, int causal)
{
    int bx = blockIdx.x, by = blockIdx.y, bz = blockIdx.z;
    if (causal == 3) {
        const int t = blockIdx.x;
        int byy = (int)((sqrtf(8.f * (float)t + 1.f) - 1.f) * 0.5f);
        while ((byy + 1) * (byy + 2) / 2 <= t) byy++;
        while (byy * (byy + 1) / 2 > t) byy--;
        by = byy; bx = t - byy * (byy + 1) / 2; bz = blockIdx.y;
    }
    if (causal == 2 && bz >= 2) by = (int)gridDim.y - 1 - by;  // pair long/short K rows per CU
    const int kend = (causal == 2) ? min(Kdim, (by + 1) * BM) : Kdim;

    A  += (long long)bz * a_bs;
    Bt += (long long)bz * b_bs;

    const int m0 = by * BM, n0 = bx * BN;
    const int tid = threadIdx.x;
    const int wave = tid >> 6, lane = tid & 63;
    const int wy = wave >> 1, wx = wave & 1;
    const int lr = lane >> 2, lc8 = (lane & 3) * 8;
    const int lane15 = lane & 15, kq = lane >> 4;

    __shared__ __align__(16) u16 As[2][BM * 32];
    __shared__ __align__(16) u16 Bs[2][BN * 32];

    f32x4 acc[4][4] = {};

    for (int k0 = 0; k0 < kend; k0 += 64) {
        __syncthreads();
        #pragma unroll
        for (int h = 0; h < 2; h++) {
            const int kh = k0 + h * 32 + lc8;
            #pragma unroll
            for (int it = 0; it < 2; it++) {
                const int row = wave * 16 + it * 64 + lr;
                gload_lds16(A  + (size_t)(m0 + row) * lda + kh,
                            &As[h][(wave * 16 + it * 64) * 32]);
                gload_lds16(Bt + (size_t)(n0 + row) * ldb + kh,
                            &Bs[h][(wave * 16 + it * 64) * 32]);
            }
        }
        __syncthreads();

        #pragma unroll
        for (int h = 0; h < 2; h++) {
            bf16x8 av[4], bv[4];
            #pragma unroll
            for (int i = 0; i < 4; i++)
                av[i] = *(const bf16x8*)&As[h][(wy * 64 + i * 16 + lane15) * 32 + kq * 8];
            #pragma unroll
            for (int j = 0; j < 4; j++)
                bv[j] = *(const bf16x8*)&Bs[h][(wx * 64 + j * 16 + lane15) * 32 + kq * 8];
            #pragma unroll
            for (int i = 0; i < 4; i++)
                #pragma unroll
                for (int j = 0; j < 4; j++)
                    acc[i][j] = __builtin_amdgcn_mfma_f32_16x16x32_bf16(av[i], bv[j], acc[i][j], 0, 0, 0);
        }
    }

    // Epilogue. C/D layout (m89-verified): col = lane&15, row = (lane>>4)*4 + reg.
    if (MODE == 6 && n0 >= 512) {
        u16* o = (u16*)resid;  // Vt[b][c-512][s], second output pointer
        #pragma unroll
        for (int i = 0; i < 4; i++) {
            const int r = m0 + wy * 64 + i * 16 + kq * 4;
            const size_t base = (size_t)(r >> 11) * 1024 * 2048 + (r & 2047);
            #pragma unroll
            for (int j = 0; j < 4; j++) {
                const int c = n0 + wx * 64 + j * 16 + lane15;
                const float bj = bias[c];
                ushort4 pk;
                pk.x = f2bf(acc[i][j][0] + bj);
                pk.y = f2bf(acc[i][j][1] + bj);
                pk.z = f2bf(acc[i][j][2] + bj);
                pk.w = f2bf(acc[i][j][3] + bj);
                *(ushort4*)&o[base + (size_t)(c - 512) * 2048] = pk;
            }
        }
    } else {
        #pragma unroll
        for (int i = 0; i < 4; i++) {
            const int rl = m0 + wy * 64 + i * 16 + kq * 4;
            #pragma unroll
            for (int j = 0; j < 4; j++) {
                const int c = n0 + wx * 64 + j * 16 + lane15;
                float bj = 0.f;
                if (MODE == 4 || MODE == 5 || MODE == 6) bj = bias[c];
                #pragma unroll
                for (int rg = 0; rg < 4; rg++) {
                    const int r = rl + rg;
                    const size_t idx = (size_t)bz * c_bs + (size_t)r * ldc + c;
                    const float v = acc[i][j][rg];
                    if (MODE == 2) {
                        float p = __expf(v * scale);
                        if (c > r) p = 0.f;          // causal mask inside diagonal tile
                        ((u16*)out)[idx] = f2bf(p);
                    } else if (MODE == 3) {
                        const u16* xr = (const u16*)resid;
                        const float linv = bias[(size_t)bz * 2048 + r];
                        const float h = bf2f(xr[(size_t)bz * r_bs + (size_t)r * ldc + c]) + v * linv;
                        ((u16*)out)[idx] = f2bf(h);
                    } else if (MODE == 4) {
                        ((u16*)out)[idx] = f2bf(fmaxf(v + bj, 0.f));
                    } else if (MODE == 5) {
                        const u16* hb = (const u16*)resid;
                        ((float*)out)[idx] = v + bj + bf2f(hb[(size_t)r * ldc + c]);
                    } else if (MODE == 6) {
                        ((u16*)out)[idx] = f2bf(v + bj);
                    }
                }
            }
        }
    }
}

// x fp32 -> bf16, vectorized (float4 in, ushort4 out).
__global__ __launch_bounds__(256)
void prep_x(const float* __restrict__ x, u16* __restrict__ xb)
{
    const int N4 = 8388608 / 4;
    for (int i = blockIdx.x * blockDim.x + threadIdx.x; i < N4; i += gridDim.x * blockDim.x) {
        const float4 v = ((const float4*)x)[i];
        ushort4 o;
        o.x = f2bf(v.x); o.y = f2bf(v.y); o.z = f2bf(v.z); o.w = f2bf(v.w);
        ((ushort4*)xb)[i] = o;
    }
}

// Coalesced LDS-tiled transpose+convert of all weights, plus bias concat.
// Blocks 0..127: Wq/Wk -> WqkT[512][1024]; 128..895: Wv/W1/W2 -> [1024][1024]T; 896: biases.
__global__ __launch_bounds__(256)
void prep_w(const float* __restrict__ Wq, const float* __restrict__ bq,
            const float* __restrict__ Wk, const float* __restrict__ bk,
            const float* __restrict__ Wv, const float* __restrict__ bv,
            const float* __restrict__ b1, const float* __restrict__ b2,
            const float* __restrict__ W1, const float* __restrict__ W2,
            u16* __restrict__ WqkT, u16* __restrict__ WvT,
            u16* __restrict__ W1T, u16* __restrict__ W2T, float* __restrict__ biasv)
{
    const int bid = blockIdx.x, tid = threadIdx.x;
    if (bid == 896) {
        for (int t = tid; t < 3584; t += 256) {
            if (t < 512)       biasv[t] = (t < 256) ? bq[t] : bk[t - 256];
            else if (t < 1536) biasv[t] = bv[t - 512];
            else if (t < 2560) biasv[t] = b1[t - 1536];
            else               biasv[t] = b2[t - 2560];
        }
        return;
    }
    const float* src; u16* dst; int ld_src, kt, nt, nbase;
    if (bid < 128) {
        const int job = bid >> 6, t = bid & 63;
        src = job ? Wk : Wq; ld_src = 256;
        kt = t >> 2; nt = t & 3; nbase = job * 256 + nt * 64;
        dst = WqkT;
    } else {
        const int j = bid - 128, w = j >> 8, t = j & 255;
        src = (w == 0) ? Wv : (w == 1) ? W1 : W2; ld_src = 1024;
        kt = t >> 4; nt = t & 15; nbase = nt * 64;
        dst = (w == 0) ? WvT : (w == 1) ? W1T : W2T;
    }
    const int k0 = kt * 64, n0 = (nbase & 255) | (nbase & ~255 & 0);  // n0 within src cols
    const int n0s = (ld_src == 256) ? (nbase & 255) : nbase;

    __shared__ float tile[64][65];
    // read 64 rows (k) x 64 cols (n), coalesced float4
    const int ri = tid >> 4, j4 = (tid & 15) * 4;
    #pragma unroll
    for (int rr = 0; rr < 4; rr++) {
        const int i = ri + rr * 16;
        const float4 v = *(const float4*)&src[(size_t)(k0 + i) * ld_src + n0s + j4];
        tile[j4 + 0][i] = v.x;
        tile[j4 + 1][i] = v.y;
        tile[j4 + 2][i] = v.z;
        tile[j4 + 3][i] = v.w;
    }
    __syncthreads();
    // write 64 n-rows x 64 k, coalesced u16
    const int n = tid >> 2, ks = (tid & 3) * 16;
    ushort4 o[4];
    #pragma unroll
    for (int c = 0; c < 4; c++) {
        o[c].x = f2bf(tile[n][ks + c * 4 + 0]);
        o[c].y = f2bf(tile[n][ks + c * 4 + 1]);
        o[c].z = f2bf(tile[n][ks + c * 4 + 2]);
        o[c].w = f2bf(tile[n][ks + c * 4 + 3]);
    }
    u16* drow = &dst[(size_t)(nbase + n) * 1024 + k0 + ks];
    #pragma unroll
    for (int c = 0; c < 4; c++) *(ushort4*)&drow[c * 4] = o[c];
}

__device__ __forceinline__ float wave_sum(float v) {
    #pragma unroll
    for (int off = 32; off > 0; off >>= 1) v += __shfl_xor(v, off, 64);
    return v;
}

// One block per (b,q) row. Fully vectorized: P has exact zeros for c in (r, kpad)
// (G3 masks the diagonal tile), so no per-element validity masking is needed.
__global__ __launch_bounds__(256)
void norm_kernel(const u16* __restrict__ attnb, float* __restrict__ attn,
                 float* __restrict__ linv)
{
    const int S = 2048;
    const int row = blockIdx.x;
    const int q = row & (S - 1);
    const int kpad = (q + 128) & ~127;   // ceil((q+1)/128)*128
    const u16* brow = attnb + (size_t)row * S;
    float* srow = attn + (size_t)row * S;
    __shared__ float red[4];
    const int tid = threadIdx.x, wv = tid >> 6, ln = tid & 63;
    const int k = tid * 8;

    float vals[8];
    float lsum = 0.f;
    if (k < kpad) {
        const ushort4 a = *(const ushort4*)&brow[k];
        const ushort4 b = *(const ushort4*)&brow[k + 4];
        vals[0] = bf2f(a.x); vals[1] = bf2f(a.y); vals[2] = bf2f(a.z); vals[3] = bf2f(a.w);
        vals[4] = bf2f(b.x); vals[5] = bf2f(b.y); vals[6] = bf2f(b.z); vals[7] = bf2f(b.w);
        #pragma unroll
        for (int c = 0; c < 8; c++) lsum += vals[c];
    }
    lsum = wave_sum(lsum);
    if (ln == 0) red[wv] = lsum;
    __syncthreads();
    const float rinv = 1.f / (red[0] + red[1] + red[2] + red[3]);

    float4 o0 = {0.f, 0.f, 0.f, 0.f}, o1 = {0.f, 0.f, 0.f, 0.f};
    if (k < kpad) {
        o0 = make_float4(vals[0] * rinv, vals[1] * rinv, vals[2] * rinv, vals[3] * rinv);
        o1 = make_float4(vals[4] * rinv, vals[5] * rinv, vals[6] * rinv, vals[7] * rinv);
    }
    *(float4*)&srow[k] = o0;
    *(float4*)&srow[k + 4] = o1;
    if (tid == 0) linv[row] = rinv;
}

extern "C" void kernel_launch(void* const* d_in, const int* in_sizes, int n_in,
                              void* d_out, int out_size, void* d_ws, size_t ws_size,
                              hipStream_t stream)
{
    const float* x  = (const float*)d_in[0];
    const float* Wq = (const float*)d_in[1];
    const float* bq = (const float*)d_in[2];
    const float* Wk = (const float*)d_in[3];
    const float* bk = (const float*)d_in[4];
    const float* Wv = (const float*)d_in[5];
    const float* bv = (const float*)d_in[6];
    const float* W1 = (const float*)d_in[7];
    const float* b1 = (const float*)d_in[8];
    const float* W2 = (const float*)d_in[9];
    const float* b2 = (const float*)d_in[10];

    const int B = 4, S = 2048, D = 1024, BS = B * S;

    char* ws = (char*)d_ws;
    u16*   xb    = (u16*)(ws + 0);            // 16 MB, aliased by h_b after G4
    u16*   WqkT  = (u16*)(ws + 16777216);     // 1 MB
    u16*   WvT   = (u16*)(ws + 17825792);     // 2 MB
    u16*   W1T   = (u16*)(ws + 19922944);     // 2 MB
    u16*   W2T   = (u16*)(ws + 22020096);     // 2 MB
    float* biasv = (float*)(ws + 24117248);   // 16 KB: [bq|bk][bv][b1][b2]
    u16*   QK    = (u16*)(ws + 24133632);     // 8 MB: [8192][512] = [Q|K]
    u16*   Vt    = (u16*)(ws + 32522240);     // 16 MB: [4][1024][2048]
    u16*   attnb = (u16*)(ws + 49299456);     // 32 MB raw exp-P, aliased by ff1 after G4
    float* linv  = (float*)(ws + 83886080);   // 32 KB
    u16*   hb    = xb;
    u16*   ff1   = attnb;

    float* out0 = (float*)d_out;
    float* attn = out0 + (size_t)BS * D;

    const dim3 blk(256);

    prep_x<<<dim3(1024), blk, 0, stream>>>(x, xb);
    prep_w<<<dim3(897), blk, 0, stream>>>(Wq, bq, Wk, bk, Wv, bv, b1, b2, W1, W2,
                                          WqkT, WvT, W1T, W2T, biasv);

    // G12 merged: [Q|K|V] = x @ [Wq|Wk|Wv] + bias   (M=8192, N=1536, K=1024, 768 blocks)
    gemm_bt<6><<<dim3(12, 64, 1), blk, 0, stream>>>(
        xb, 1024, 0, WqkT, 1024, 0, 1024, 512, 0,
        biasv, 1.f, Vt, 0, QK, 0);

    // G3: P = exp(Q @ K^T / 16), causal-masked, bf16, triangular grid (544 blocks)
    gemm_bt<2><<<dim3(136, 4, 1), blk, 0, stream>>>(
        QK, 512, (long long)S * 512, QK + 256, 512, (long long)S * 512,
        256, S, (long long)S * S, nullptr, 0.0625f, nullptr, 0, attnb, 3);

    // normalize: attn_fp32 = P / l (d_out), linv = 1/l
    norm_kernel<<<dim3(BS), blk, 0, stream>>>(attnb, attn, linv);

    // G4: h = bf16(x) + (P @ V) * linv  (512 blocks, K clipped at diagonal, by-pairing)
    gemm_bt<3><<<dim3(8, 16, 4), blk, 0, stream>>>(
        attnb, S, (long long)S * S, Vt, S, (long long)D * S,
        S, D, (long long)S * D, linv, 1.f, xb, (long long)S * D, hb, 2);

    // G5: ff1 = relu(h @ W1 + b1)  (M=8192, N=1024, K=1024)
    gemm_bt<4><<<dim3(8, 64, 1), blk, 0, stream>>>(
        hb, 1024, 0, W1T, 1024, 0, 1024, 1024, 0,
        biasv + 1536, 1.f, nullptr, 0, ff1, 0);

    // G6: out0 = h + ff1 @ W2 + b2  (M=8192, N=1024, K=1024)
    gemm_bt<5><<<dim3(8, 64, 1), blk, 0, stream>>>(
        ff1, 1024, 0, W2T, 1024, 0, 1024, 1024, 0,
        biasv + 2560, 1.f, hb, 0, out0, 0);
}